// Round 4
// baseline (2219.614 us; speedup 1.0000x reference)
//
#include <hip/hip_runtime.h>
#include <math.h>

#define INDIM 64
#define HID 32

// Build segment start offsets from the sorted batch array.
// off[b] = first index i with batch[i] >= b ; off[nseg] = n.
__global__ void seg_offsets_kernel(const int* __restrict__ batch, int n, int nseg,
                                   int* __restrict__ off) {
    int i = blockIdx.x * blockDim.x + threadIdx.x;
    if (i >= n) return;
    int cur = batch[i];
    int prev = (i == 0) ? -1 : batch[i - 1];
    for (int b = prev + 1; b <= cur; ++b) off[b] = i;
    if (i == n - 1) {
        for (int b = cur + 1; b <= nseg; ++b) off[b] = n;
    }
}

static __device__ __forceinline__ float readlane_f(float v, int l) {
    return __int_as_float(__builtin_amdgcn_readlane(__float_as_int(v), l));
}

// One WAVE per segment; 4 waves (4 independent segments) per 256-thread block.
// Zero barriers after weight staging. Per 64-row chunk:
//   - gate MLP row-per-lane (x row in 16 float4 regs, weights LDS-broadcast)
//   - weighted column accumulate: lane k sums e_r * x[r][k]; e via v_readlane,
//     x re-read from global (L1-hot: the gate just fetched these lines)
//   - prefetch next chunk's rows (overlaps next-gate latency)
// No max-subtraction: |g| < ~2 with 0.1-scaled weights, exp(g) is safe and
// alpha = exp(g)/sum matches the reference to ~1 ulp (R1/R2: absmax 0.0).
__global__ __launch_bounds__(256, 4) void fused_seg_attn_kernel(
    const float* __restrict__ x,
    const int* __restrict__ off,
    const float* __restrict__ Wg1, const float* __restrict__ bg1,
    const float* __restrict__ Wg2, const float* __restrict__ bg2,
    const float* __restrict__ Wm1, const float* __restrict__ bm1,
    const float* __restrict__ Wm2, const float* __restrict__ bm2,
    float* __restrict__ out, int nseg)
{
    __shared__ float4 wg1s[INDIM][HID / 4];   // 8 KB, wave-uniform broadcast reads
    __shared__ float  wg2s[HID];
    __shared__ float  bg1s[HID];

    const int tid  = threadIdx.x;
    const int lane = tid & 63;
    const int wid  = tid >> 6;

    for (int i = tid; i < INDIM * (HID / 4); i += 256)
        ((float4*)wg1s)[i] = ((const float4*)Wg1)[i];
    if (tid < HID) { wg2s[tid] = Wg2[tid]; bg1s[tid] = bg1[tid]; }
    __syncthreads();   // weights staged; no further barriers

    const int seg = blockIdx.x * 4 + wid;
    if (seg >= nseg) return;
    const int s0 = off[seg];
    const int s1 = off[seg + 1];
    const float bg2v = bg2[0];

    float colsum = 0.f;   // lane k accumulates sum_r e_r * x[r][k]
    float esum   = 0.f;

    if (s1 > s0) {
        float4 xv[16];
        {   // prologue: first chunk's row -> registers
            int r = s0 + lane; if (r >= s1) r = s1 - 1;
            const float4* xrow = reinterpret_cast<const float4*>(x + (size_t)r * INDIM);
            #pragma unroll
            for (int k4 = 0; k4 < 16; ++k4) xv[k4] = xrow[k4];
        }

        for (int base = s0; base < s1; base += 64) {
            const bool active = (base + lane < s1);

            // ---- gate MLP: h = relu(x_row @ Wg1 + bg1); g = h @ Wg2 + bg2
            float acc[HID];
            #pragma unroll
            for (int j = 0; j < HID; ++j) acc[j] = bg1s[j];
            #pragma unroll
            for (int k4 = 0; k4 < 16; ++k4) {
                #pragma unroll
                for (int kk = 0; kk < 4; ++kk) {
                    const float xk = (kk == 0) ? xv[k4].x : (kk == 1) ? xv[k4].y
                                   : (kk == 2) ? xv[k4].z : xv[k4].w;
                    const int k = k4 * 4 + kk;
                    #pragma unroll
                    for (int j4 = 0; j4 < HID / 4; ++j4) {
                        const float4 w = wg1s[k][j4];   // LDS broadcast
                        acc[j4 * 4 + 0] = fmaf(xk, w.x, acc[j4 * 4 + 0]);
                        acc[j4 * 4 + 1] = fmaf(xk, w.y, acc[j4 * 4 + 1]);
                        acc[j4 * 4 + 2] = fmaf(xk, w.z, acc[j4 * 4 + 2]);
                        acc[j4 * 4 + 3] = fmaf(xk, w.w, acc[j4 * 4 + 3]);
                    }
                }
            }
            float gs = 0.f;
            #pragma unroll
            for (int j = 0; j < HID; ++j)
                gs = fmaf(fmaxf(acc[j], 0.f), wg2s[j], gs);
            const float e = active ? __expf(gs + bg2v) : 0.f;
            esum += e;

            // ---- weighted column accumulate (x from global, L1-hot)
            const int cnt = (s1 - base < 64) ? (s1 - base) : 64;
            const float* xcol = x + (size_t)base * INDIM + lane;
            if (cnt == 64) {
                float p0 = 0.f, p1 = 0.f, p2 = 0.f, p3 = 0.f;
                float p4 = 0.f, p5 = 0.f, p6 = 0.f, p7 = 0.f;
                #pragma unroll
                for (int j8 = 0; j8 < 8; ++j8) {
                    const int j = j8 * 8;
                    p0 = fmaf(readlane_f(e, j + 0), xcol[(j + 0) * INDIM], p0);
                    p1 = fmaf(readlane_f(e, j + 1), xcol[(j + 1) * INDIM], p1);
                    p2 = fmaf(readlane_f(e, j + 2), xcol[(j + 2) * INDIM], p2);
                    p3 = fmaf(readlane_f(e, j + 3), xcol[(j + 3) * INDIM], p3);
                    p4 = fmaf(readlane_f(e, j + 4), xcol[(j + 4) * INDIM], p4);
                    p5 = fmaf(readlane_f(e, j + 5), xcol[(j + 5) * INDIM], p5);
                    p6 = fmaf(readlane_f(e, j + 6), xcol[(j + 6) * INDIM], p6);
                    p7 = fmaf(readlane_f(e, j + 7), xcol[(j + 7) * INDIM], p7);
                }
                colsum += ((p0 + p1) + (p2 + p3)) + ((p4 + p5) + (p6 + p7));
            } else {
                for (int j = 0; j < cnt; ++j)
                    colsum = fmaf(readlane_f(e, j), xcol[j * INDIM], colsum);
            }

            // ---- prefetch next chunk's row into xv (overlaps latency)
            const int nb = base + 64;
            if (nb < s1) {   // wave-uniform branch
                int r = nb + lane; if (r >= s1) r = s1 - 1;
                const float4* xrow = reinterpret_cast<const float4*>(x + (size_t)r * INDIM);
                #pragma unroll
                for (int k4 = 0; k4 < 16; ++k4) xv[k4] = xrow[k4];
            }
        }
    }

    // wave-reduce total e-sum; lane k then holds hg[k]
    #pragma unroll
    for (int d = 1; d < 64; d <<= 1) esum += __shfl_xor(esum, d);
    const float inv = (esum > 0.f) ? (1.f / esum) : 0.f;   // empty seg -> hg = 0
    const float hgv = colsum * inv;

    // final MLP: logit = relu(hg @ Wm1 + bm1) @ Wm2 + bm2  (lanes 32..63 mirror)
    const int h = lane & 31;
    float a = bm1[h];
    #pragma unroll
    for (int k = 0; k < INDIM; ++k)
        a = fmaf(readlane_f(hgv, k), Wm1[k * HID + h], a);
    float vv = fmaxf(a, 0.f) * Wm2[h];
    #pragma unroll
    for (int d = 1; d < 32; d <<= 1) vv += __shfl_xor(vv, d);
    if (lane == 0) out[seg] = vv + bm2[0];
}

extern "C" void kernel_launch(void* const* d_in, const int* in_sizes, int n_in,
                              void* d_out, int out_size, void* d_ws, size_t ws_size,
                              hipStream_t stream) {
    const float* x     = (const float*)d_in[0];
    const int*   batch = (const int*)d_in[1];
    const float* Wg1   = (const float*)d_in[2];
    const float* bg1   = (const float*)d_in[3];
    const float* Wg2   = (const float*)d_in[4];
    const float* bg2   = (const float*)d_in[5];
    const float* Wm1   = (const float*)d_in[6];
    const float* bm1   = (const float*)d_in[7];
    const float* Wm2   = (const float*)d_in[8];
    const float* bm2   = (const float*)d_in[9];
    float* out = (float*)d_out;

    const int n    = in_sizes[1];   // 819200 points
    const int nseg = out_size;      // 4096 segments

    int* off = (int*)d_ws;          // (nseg+1) ints of scratch
    seg_offsets_kernel<<<(n + 255) / 256, 256, 0, stream>>>(batch, n, nseg, off);
    const int nblk = (nseg + 3) / 4;   // one wave per segment
    fused_seg_attn_kernel<<<nblk, 256, 0, stream>>>(
        x, off, Wg1, bg1, Wg2, bg2, Wm1, bm1, Wm2, bm2, out, nseg);
}